// Round 1
// baseline (502.561 us; speedup 1.0000x reference)
//
#include <hip/hip_runtime.h>
#include <hip/hip_bf16.h>

// Problem constants (fixed by reference)
#define DIM      64
#define NCODE    1024
#define NROWS    131072          // 32*64*64
#define BLK      256
#define CHUNK    128             // codes staged per LDS chunk
#define LDE      68              // padded float stride per code row in LDS (68*4=272B, 16B aligned)

// Output layout (concatenated in reference return order, all f32):
//   [0 .. 8388607]            quantize
//   [8388608]                 diff (scalar mean)
//   [8388609 .. 8520680]      embed_ind (as float)
//   [8520681? no ->]          num_used at 8388609+131072 = 8519681
#define Q_OFF    0
#define DIFF_OFF 8388608
#define IND_OFF  8388609
#define NU_OFF   (8388609 + 131072)   // 8519681

// ---------------------------------------------------------------------------
// Prep: embedT[c][d] = embed[d][c];  hee[c] = 0.5 * sum_d embed[d][c]^2
// embed layout: [DIM][NCODE] row-major -> code c is a column.
__global__ __launch_bounds__(256) void vq_prep(const float* __restrict__ embed,
                                               float* __restrict__ embedT,
                                               float* __restrict__ hee) {
    int c = blockIdx.x * blockDim.x + threadIdx.x;   // 0..1023
    if (c >= NCODE) return;
    float s = 0.f;
#pragma unroll
    for (int d = 0; d < DIM; ++d) {
        float v = embed[d * NCODE + c];              // coalesced across lanes
        embedT[c * DIM + d] = v;
        s = fmaf(v, v, s);
    }
    hee[c] = 0.5f * s;
}

// ---------------------------------------------------------------------------
// Main: one thread per row. x row in regs; embed chunks staged in LDS.
__global__ __launch_bounds__(256) void vq_main(const float* __restrict__ input,
                                               const float* __restrict__ embedT,
                                               const float* __restrict__ hee,
                                               float* __restrict__ out_q,
                                               float* __restrict__ out_ind,
                                               float* __restrict__ partials) {
    __shared__ float lds_e[CHUNK * LDE];
    __shared__ float lds_hee[CHUNK];
    __shared__ float wsum[4];

    const int tid = threadIdx.x;
    const int r   = blockIdx.x * BLK + tid;          // row index, grid covers exactly NROWS

    // Load this row's x into registers (16 x float4 = 64 floats).
    float4 xv[16];
    {
        const float4* xin = (const float4*)(input + (size_t)r * DIM);
#pragma unroll
        for (int k = 0; k < 16; ++k) xv[k] = xin[k];
    }

    float best = -3.402823466e+38f;   // argmax of (dot - 0.5*||e||^2)
    int   bidx = 0;

    for (int c0 = 0; c0 < NCODE; c0 += CHUNK) {
        __syncthreads();
        // Stage CHUNK code rows (contiguous in embedT) into padded LDS.
        {
            const float4* src = (const float4*)(embedT + (size_t)c0 * DIM);
            float4* dst = (float4*)lds_e;
#pragma unroll
            for (int i = 0; i < (CHUNK * DIM / 4) / BLK; ++i) {   // 8 iters
                int j  = tid + i * BLK;       // float4 index within chunk
                int c  = j >> 4;              // 16 float4 per code
                int d4 = j & 15;
                dst[c * (LDE / 4) + d4] = src[j];
            }
            if (tid < CHUNK) lds_hee[tid] = hee[c0 + tid];
        }
        __syncthreads();

#pragma unroll 2
        for (int c = 0; c < CHUNK; ++c) {
            const float4* e4 = (const float4*)&lds_e[c * LDE];    // wave-uniform -> broadcast
            float a0 = -lds_hee[c], a1 = 0.f, a2 = 0.f, a3 = 0.f;
#pragma unroll
            for (int k = 0; k < 4; ++k) {
                float4 e0 = e4[4 * k + 0];
                float4 e1 = e4[4 * k + 1];
                float4 e2 = e4[4 * k + 2];
                float4 e3 = e4[4 * k + 3];
                float4 x0 = xv[4 * k + 0];
                float4 x1 = xv[4 * k + 1];
                float4 x2 = xv[4 * k + 2];
                float4 x3 = xv[4 * k + 3];
                a0 = fmaf(e0.x, x0.x, a0); a0 = fmaf(e0.y, x0.y, a0);
                a0 = fmaf(e0.z, x0.z, a0); a0 = fmaf(e0.w, x0.w, a0);
                a1 = fmaf(e1.x, x1.x, a1); a1 = fmaf(e1.y, x1.y, a1);
                a1 = fmaf(e1.z, x1.z, a1); a1 = fmaf(e1.w, x1.w, a1);
                a2 = fmaf(e2.x, x2.x, a2); a2 = fmaf(e2.y, x2.y, a2);
                a2 = fmaf(e2.z, x2.z, a2); a2 = fmaf(e2.w, x2.w, a2);
                a3 = fmaf(e3.x, x3.x, a3); a3 = fmaf(e3.y, x3.y, a3);
                a3 = fmaf(e3.z, x3.z, a3); a3 = fmaf(e3.w, x3.w, a3);
            }
            float s = (a0 + a1) + (a2 + a3);
            // strict > with ascending c == first-index tie-break of argmin(dist)
            if (s > best) { best = s; bidx = c0 + c; }
        }
    }

    // Epilogue: gather code row, write quantize + ind, accumulate MSE partial.
    out_ind[r] = (float)bidx;

    float acc = 0.f;
    {
        const float4* q4 = (const float4*)(embedT + (size_t)bidx * DIM);
        float4* o4 = (float4*)(out_q + (size_t)r * DIM);
#pragma unroll
        for (int k = 0; k < 16; ++k) {
            float4 q = q4[k];
            float4 x = xv[k];
            o4[k] = q;
            float dx = q.x - x.x; acc = fmaf(dx, dx, acc);
            dx = q.y - x.y;       acc = fmaf(dx, dx, acc);
            dx = q.z - x.z;       acc = fmaf(dx, dx, acc);
            dx = q.w - x.w;       acc = fmaf(dx, dx, acc);
        }
    }
    // wave reduce (64 lanes), then block reduce -> deterministic partial
#pragma unroll
    for (int off = 32; off > 0; off >>= 1) acc += __shfl_down(acc, off, 64);
    if ((tid & 63) == 0) wsum[tid >> 6] = acc;
    __syncthreads();
    if (tid == 0) partials[blockIdx.x] = (wsum[0] + wsum[1]) + (wsum[2] + wsum[3]);
}

// ---------------------------------------------------------------------------
// Finalize: deterministic reduction of 512 block partials -> mean; write -1.
__global__ __launch_bounds__(256) void vq_finalize(const float* __restrict__ partials,
                                                   float* __restrict__ out,
                                                   int out_size) {
    __shared__ float sm[256];
    int t = threadIdx.x;
    float v = partials[t] + partials[t + 256];
    sm[t] = v;
    __syncthreads();
    for (int s = 128; s > 0; s >>= 1) {
        if (t < s) sm[t] += sm[t + s];
        __syncthreads();
    }
    if (t == 0) out[DIFF_OFF] = sm[0] / 8388608.0f;
    if (t == 1 && out_size > NU_OFF) out[NU_OFF] = -1.0f;
}

// ---------------------------------------------------------------------------
extern "C" void kernel_launch(void* const* d_in, const int* in_sizes, int n_in,
                              void* d_out, int out_size, void* d_ws, size_t ws_size,
                              hipStream_t stream) {
    const float* input = (const float*)d_in[0];   // [32,64,64,64]
    const float* embed = (const float*)d_in[1];   // [64,1024]
    float* out = (float*)d_out;

    float* hee      = (float*)d_ws;               // 1024
    float* embedT   = hee + NCODE;                // 1024*64
    float* partials = embedT + NCODE * DIM;       // 512

    vq_prep<<<NCODE / 256, 256, 0, stream>>>(embed, embedT, hee);
    vq_main<<<NROWS / BLK, BLK, 0, stream>>>(input, embedT, hee,
                                             out + Q_OFF, out + IND_OFF, partials);
    vq_finalize<<<1, 256, 0, stream>>>(partials, out, out_size);
}

// Round 3
// 291.308 us; speedup vs baseline: 1.7252x; 1.7252x over previous
//
#include <hip/hip_runtime.h>
#include <hip/hip_bf16.h>

// Problem constants (fixed by reference)
#define DIM      64
#define NCODE    1024
#define NROWS    131072          // 32*64*64
#define BLK      256
#define CHUNK    128             // codes staged per LDS chunk
#define LDE      68              // padded float stride per code row in LDS
#define SPLIT    2               // code-dimension split across blocks
#define SCODES   (NCODE / SPLIT) // codes handled per block (512)

// Output layout (concatenated in reference return order, all f32):
#define Q_OFF    0
#define DIFF_OFF 8388608
#define IND_OFF  8388609
#define NU_OFF   (8388609 + 131072)   // 8519681

// ---------------------------------------------------------------------------
// Prep: embedT[c][d] = embed[d][c];  hee[c] = 0.5 * sum_d embed[d][c]^2
__global__ __launch_bounds__(256) void vq_prep(const float* __restrict__ embed,
                                               float* __restrict__ embedT,
                                               float* __restrict__ hee) {
    int c = blockIdx.x * blockDim.x + threadIdx.x;   // 0..1023
    if (c >= NCODE) return;
    float s = 0.f;
#pragma unroll
    for (int d = 0; d < DIM; ++d) {
        float v = embed[d * NCODE + c];              // coalesced across lanes
        embedT[c * DIM + d] = v;
        s = fmaf(v, v, s);
    }
    hee[c] = 0.5f * s;
}

// ---------------------------------------------------------------------------
// Scoring: each thread owns TWO rows (r, r+256); block scores 512 rows x
// 512 codes (code-group by blockIdx.y). Partial (best,idx) -> workspace.
__global__ __launch_bounds__(256, 2) void vq_score(const float* __restrict__ input,
                                                   const float* __restrict__ embedT,
                                                   const float* __restrict__ hee,
                                                   float* __restrict__ pbest,
                                                   float* __restrict__ pidx) {
    __shared__ float lds_e[CHUNK * LDE];
    __shared__ float lds_hee[CHUNK];

    const int tid   = threadIdx.x;
    const int r0    = blockIdx.x * (2 * BLK) + tid;      // row A
    const int r1    = r0 + BLK;                          // row B
    const int cbase = blockIdx.y * SCODES;               // code-group base

    // Both x rows into registers: 32 x float4 = 128 VGPRs.
    float4 xa[16], xb[16];
    {
        const float4* pa = (const float4*)(input + (size_t)r0 * DIM);
        const float4* pb = (const float4*)(input + (size_t)r1 * DIM);
#pragma unroll
        for (int k = 0; k < 16; ++k) { xa[k] = pa[k]; xb[k] = pb[k]; }
    }

    float bestA = -3.402823466e+38f, bestB = -3.402823466e+38f;
    int   idxA = 0, idxB = 0;

    for (int c0 = 0; c0 < SCODES; c0 += CHUNK) {
        __syncthreads();
        // Stage CHUNK code rows into padded LDS (contiguous global reads).
        {
            const float4* src = (const float4*)(embedT + (size_t)(cbase + c0) * DIM);
            float4* dst = (float4*)lds_e;
#pragma unroll
            for (int i = 0; i < (CHUNK * DIM / 4) / BLK; ++i) {   // 8 iters
                int j  = tid + i * BLK;       // float4 index within chunk
                int c  = j >> 4;              // 16 float4 per code
                int d4 = j & 15;
                dst[c * (LDE / 4) + d4] = src[j];
            }
            if (tid < CHUNK) lds_hee[tid] = hee[cbase + c0 + tid];
        }
        __syncthreads();

#pragma unroll 2
        for (int c = 0; c < CHUNK; ++c) {
            const float4* e4 = (const float4*)&lds_e[c * LDE];    // wave-uniform
            float hh = lds_hee[c];
            // Same 4-chain grouping as the baseline (identical rounding per row).
            float a0 = -hh, a1 = 0.f, a2 = 0.f, a3 = 0.f;
            float b0 = -hh, b1 = 0.f, b2 = 0.f, b3 = 0.f;
#pragma unroll
            for (int k = 0; k < 16; ++k) {
                float4 e = e4[k];
                float4 p = xa[k];
                float4 q = xb[k];
                switch (k & 3) {
                case 0:
                    a0 = fmaf(e.x, p.x, a0); a0 = fmaf(e.y, p.y, a0);
                    a0 = fmaf(e.z, p.z, a0); a0 = fmaf(e.w, p.w, a0);
                    b0 = fmaf(e.x, q.x, b0); b0 = fmaf(e.y, q.y, b0);
                    b0 = fmaf(e.z, q.z, b0); b0 = fmaf(e.w, q.w, b0);
                    break;
                case 1:
                    a1 = fmaf(e.x, p.x, a1); a1 = fmaf(e.y, p.y, a1);
                    a1 = fmaf(e.z, p.z, a1); a1 = fmaf(e.w, p.w, a1);
                    b1 = fmaf(e.x, q.x, b1); b1 = fmaf(e.y, q.y, b1);
                    b1 = fmaf(e.z, q.z, b1); b1 = fmaf(e.w, q.w, b1);
                    break;
                case 2:
                    a2 = fmaf(e.x, p.x, a2); a2 = fmaf(e.y, p.y, a2);
                    a2 = fmaf(e.z, p.z, a2); a2 = fmaf(e.w, p.w, a2);
                    b2 = fmaf(e.x, q.x, b2); b2 = fmaf(e.y, q.y, b2);
                    b2 = fmaf(e.z, q.z, b2); b2 = fmaf(e.w, q.w, b2);
                    break;
                default:
                    a3 = fmaf(e.x, p.x, a3); a3 = fmaf(e.y, p.y, a3);
                    a3 = fmaf(e.z, p.z, a3); a3 = fmaf(e.w, p.w, a3);
                    b3 = fmaf(e.x, q.x, b3); b3 = fmaf(e.y, q.y, b3);
                    b3 = fmaf(e.z, q.z, b3); b3 = fmaf(e.w, q.w, b3);
                    break;
                }
            }
            float sA = (a0 + a1) + (a2 + a3);
            float sB = (b0 + b1) + (b2 + b3);
            int code = cbase + c0 + c;
            if (sA > bestA) { bestA = sA; idxA = code; }
            if (sB > bestB) { bestB = sB; idxB = code; }
        }
    }

    // Partial results, coalesced.
    size_t o = (size_t)blockIdx.y * NROWS;
    pbest[o + r0] = bestA;  pidx[o + r0] = (float)idxA;
    pbest[o + r1] = bestB;  pidx[o + r1] = (float)idxB;
}

// ---------------------------------------------------------------------------
// Combine: merge the SPLIT partials per row, gather code row, write outputs,
// accumulate deterministic MSE partial per block.
__global__ __launch_bounds__(256) void vq_combine(const float* __restrict__ input,
                                                  const float* __restrict__ embedT,
                                                  const float* __restrict__ pbest,
                                                  const float* __restrict__ pidx,
                                                  float* __restrict__ out_q,
                                                  float* __restrict__ out_ind,
                                                  float* __restrict__ partials) {
    __shared__ float wsum[4];
    const int tid = threadIdx.x;
    const int r   = blockIdx.x * BLK + tid;

    float p0 = pbest[r];
    float p1 = pbest[(size_t)NROWS + r];
    int   i0 = (int)pidx[r];
    int   i1 = (int)pidx[(size_t)NROWS + r];
    // strict > keeps lower index on exact tie (group-0 codes < group-1 codes)
    int bi = (p1 > p0) ? i1 : i0;
    out_ind[r] = (float)bi;

    float acc = 0.f;
    {
        const float4* x4 = (const float4*)(input + (size_t)r * DIM);
        const float4* q4 = (const float4*)(embedT + (size_t)bi * DIM);
        float4* o4 = (float4*)(out_q + (size_t)r * DIM);
#pragma unroll
        for (int k = 0; k < 16; ++k) {
            float4 q = q4[k];
            float4 x = x4[k];
            o4[k] = q;
            float dx = q.x - x.x; acc = fmaf(dx, dx, acc);
            dx = q.y - x.y;       acc = fmaf(dx, dx, acc);
            dx = q.z - x.z;       acc = fmaf(dx, dx, acc);
            dx = q.w - x.w;       acc = fmaf(dx, dx, acc);
        }
    }
#pragma unroll
    for (int off = 32; off > 0; off >>= 1) acc += __shfl_down(acc, off, 64);
    if ((tid & 63) == 0) wsum[tid >> 6] = acc;
    __syncthreads();
    if (tid == 0) partials[blockIdx.x] = (wsum[0] + wsum[1]) + (wsum[2] + wsum[3]);
}

// ---------------------------------------------------------------------------
// Finalize: deterministic reduction of 512 block partials -> mean; write -1.
__global__ __launch_bounds__(256) void vq_finalize(const float* __restrict__ partials,
                                                   float* __restrict__ out,
                                                   int out_size) {
    __shared__ float sm[256];
    int t = threadIdx.x;
    float v = partials[t] + partials[t + 256];
    sm[t] = v;
    __syncthreads();
    for (int s = 128; s > 0; s >>= 1) {
        if (t < s) sm[t] += sm[t + s];
        __syncthreads();
    }
    if (t == 0) out[DIFF_OFF] = sm[0] / 8388608.0f;
    if (t == 1 && out_size > NU_OFF) out[NU_OFF] = -1.0f;
}

// ---------------------------------------------------------------------------
extern "C" void kernel_launch(void* const* d_in, const int* in_sizes, int n_in,
                              void* d_out, int out_size, void* d_ws, size_t ws_size,
                              hipStream_t stream) {
    const float* input = (const float*)d_in[0];   // [32,64,64,64]
    const float* embed = (const float*)d_in[1];   // [64,1024]
    float* out = (float*)d_out;

    float* hee      = (float*)d_ws;               // 1024
    float* embedT   = hee + NCODE;                // 1024*64
    float* partials = embedT + NCODE * DIM;       // 512
    float* pbest    = partials + 512;             // SPLIT * NROWS
    float* pidx     = pbest + (size_t)SPLIT * NROWS;  // SPLIT * NROWS

    vq_prep<<<NCODE / 256, 256, 0, stream>>>(embed, embedT, hee);
    dim3 sgrid(NROWS / (2 * BLK), SPLIT);         // (256, 2)
    vq_score<<<sgrid, BLK, 0, stream>>>(input, embedT, hee, pbest, pidx);
    vq_combine<<<NROWS / BLK, BLK, 0, stream>>>(input, embedT, pbest, pidx,
                                                out + Q_OFF, out + IND_OFF, partials);
    vq_finalize<<<1, 256, 0, stream>>>(partials, out, out_size);
}